// Round 4
// baseline (3646.546 us; speedup 1.0000x reference)
//
#include <hip/hip_runtime.h>

#define T_STEPS 512
#define BATCH   128
#define DIN     256
#define DLAT    512

typedef __bf16 bf16x8 __attribute__((ext_vector_type(8)));
typedef float  f32x4  __attribute__((ext_vector_type(4)));
typedef int    i32x4  __attribute__((ext_vector_type(4)));

__device__ __forceinline__ unsigned int f2bf2(float a, float b) {
  unsigned int ua = __float_as_uint(a);
  unsigned int ub = __float_as_uint(b);
  ua = (ua + 0x7FFFu + ((ua >> 16) & 1u)) >> 16;
  ub = (ub + 0x7FFFu + ((ub >> 16) & 1u)) >> 16;
  return ua | (ub << 16);
}

__device__ __forceinline__ uint4 pack8(float4 f0, float4 f1) {
  uint4 r;
  r.x = f2bf2(f0.x, f0.y);
  r.y = f2bf2(f0.z, f0.w);
  r.z = f2bf2(f1.x, f1.y);
  r.w = f2bf2(f1.z, f1.w);
  return r;
}

// ---------------- Kernel A: Xi = X @ Wi^T + (bi + bh), written into d_out ----------------
// Tile 128x128, full K=256 staged in LDS as bf16 (swizzled), 4 waves of 64x64.
extern "C" __global__ __launch_bounds__(256) void xi_gemm(
    const float* __restrict__ X, const float* __restrict__ Wi,
    const float* __restrict__ bi, const float* __restrict__ bh,
    float* __restrict__ XiOut) {
  extern __shared__ char smem[];
  char*  sX    = smem;                      // 65536 B: [128 rows][512 B] swizzled
  char*  sW    = smem + 65536;              // 65536 B
  float* sBias = (float*)(smem + 131072);   // 128 floats

  const int tid = threadIdx.x;
  const long m0 = (long)blockIdx.x * 128;   // over T*B = 65536
  const int  n0 = blockIdx.y * 128;         // over DLAT

  // stage X / Wi tiles (fp32 -> bf16), 16-B swizzled chunks
  // 128 rows x 256 elems = 4096 chunks of 8 -> 16 iters x 256 threads
  #pragma unroll
  for (int c = 0; c < 16; ++c) {
    int id = c * 256 + tid;                 // 0..4095
    int r  = id >> 5;                       // 0..127
    int kc = (id & 31) << 3;                // 0..248
    const float* sx = X + (m0 + r) * DIN + kc;
    float4 a0 = *(const float4*)sx;
    float4 a1 = *(const float4*)(sx + 4);
    int ax = (r << 9) + (kc << 1);
    ax ^= (r & 7) << 4;
    *(uint4*)(sX + ax) = pack8(a0, a1);
    const float* sw = Wi + (n0 + r) * DIN + kc;
    float4 b0 = *(const float4*)sw;
    float4 b1 = *(const float4*)(sw + 4);
    *(uint4*)(sW + ax) = pack8(b0, b1);
  }
  if (tid < 128) sBias[tid] = bi[n0 + tid] + bh[n0 + tid];
  __syncthreads();

  const int w = tid >> 6, lane = tid & 63;
  const int wm = (w >> 1) * 64, wn = (w & 1) * 64;
  const int lm = lane & 15, lq = lane >> 4;

  f32x4 acc[4][4];
  #pragma unroll
  for (int nt = 0; nt < 4; ++nt) {
    float bv = sBias[wn + nt * 16 + lm];
    #pragma unroll
    for (int mt = 0; mt < 4; ++mt) acc[mt][nt] = f32x4{bv, bv, bv, bv};
  }

  #pragma unroll
  for (int k0 = 0; k0 < 8; ++k0) {
    int kb = (k0 << 6) + (lq << 4);
    bf16x8 af[4], bfr[4];
    #pragma unroll
    for (int mt = 0; mt < 4; ++mt) {
      int row = wm + mt * 16 + lm;
      int ax = (row << 9) + kb;
      ax ^= (row & 7) << 4;
      af[mt] = __builtin_bit_cast(bf16x8, *(uint4*)(sX + ax));
    }
    #pragma unroll
    for (int nt = 0; nt < 4; ++nt) {
      int row = wn + nt * 16 + lm;
      int ax = (row << 9) + kb;
      ax ^= (row & 7) << 4;
      bfr[nt] = __builtin_bit_cast(bf16x8, *(uint4*)(sW + ax));
    }
    #pragma unroll
    for (int mt = 0; mt < 4; ++mt)
      #pragma unroll
      for (int nt = 0; nt < 4; ++nt)
        acc[mt][nt] = __builtin_amdgcn_mfma_f32_16x16x32_bf16(af[mt], bfr[nt], acc[mt][nt], 0, 0, 0);
  }

  // D[r=m][c=n]: lane holds col n = nt*16+lm, rows m = mt*16 + 4*lq + e
  #pragma unroll
  for (int mt = 0; mt < 4; ++mt) {
    #pragma unroll
    for (int e = 0; e < 4; ++e) {
      long m = m0 + wm + mt * 16 + (lq << 2) + e;
      float* dst = XiOut + m * DLAT + n0 + wn + lm;
      #pragma unroll
      for (int nt = 0; nt < 4; ++nt)
        dst[nt * 16] = acc[mt][nt][e];
    }
  }
}

// ---------------- Kernel B: persistent recurrence, 8 blocks x 16 batch rows ----------------
// Wh resident: k-tiles 0..11 PINNED IN AGPRs (192 regs/thread), k-tiles 12..15 in LDS
// (128 KB). h in single swizzled LDS buffer (16 KB). In-place: reads Xi from HO, writes
// h_t back.
// Round-3 lesson: __launch_bounds__(512,2) did NOT raise the allocator's 128-reg target;
// wreg spilled to scratch (-> 384 KB/CU/step reloads = the whole 5 us/step). Fix:
// (a) amdgpu_waves_per_eu(2,2) pins the occupancy target to our real occupancy
//     (1 block/CU is already forced by 144 KB LDS), budget = 256 regs/wave;
// (b) empty-asm "+a" pins force wreg into AGPRs, which the MFMA A-operand reads
//     directly (gfx950 unified RF) - arch VGPRs stay free for acc/xi/addressing.
extern "C" __global__ __launch_bounds__(512)
__attribute__((amdgpu_waves_per_eu(2, 2)))
void rnn_scan(
    const float* __restrict__ h0, const float* __restrict__ Wh,
    float* __restrict__ HO) {
  extern __shared__ char smem[];
  char* sWh = smem;             // 131072 B: [n=512][256 B], k in [384,512), swizzled
  char* sH  = smem + 131072;    // 16384 B:  [m=16][1024 B], swizzled

  const int tid = threadIdx.x;
  const int w = tid >> 6, lane = tid & 63;
  const int lm = lane & 15, lq = lane >> 4;
  const int r0 = blockIdx.x << 4;

  // Wh register fragments (A-operand): lane holds Wh[n = w*64+t0*16+lm][k0*32+8*lq .. +7]
  i32x4 wreg[4][12];
  #pragma unroll
  for (int t0 = 0; t0 < 4; ++t0) {
    const float* base = Wh + (w * 64 + t0 * 16 + lm) * DLAT + (lq << 3);
    #pragma unroll
    for (int k0 = 0; k0 < 12; ++k0) {
      const float* src = base + k0 * 32;
      float4 f0 = *(const float4*)src;
      float4 f1 = *(const float4*)(src + 4);
      wreg[t0][k0] = __builtin_bit_cast(i32x4, pack8(f0, f1));
    }
  }
  // Pin the resident Wh fragments into AGPRs (kept there across the whole t-loop).
  #pragma unroll
  for (int t0 = 0; t0 < 4; ++t0)
    #pragma unroll
    for (int k0 = 0; k0 < 12; ++k0)
      asm("" : "+a"(wreg[t0][k0]));

  // Wh LDS region: k in [384,512)
  #pragma unroll
  for (int c = 0; c < 16; ++c) {
    int id = c * 512 + tid;                 // 0..8191
    int n = id >> 4, kc = (id & 15) << 3;   // kc 0..120
    const float* src = Wh + n * DLAT + 384 + kc;
    float4 f0 = *(const float4*)src;
    float4 f1 = *(const float4*)(src + 4);
    int ax = (n << 8) + (kc << 1);
    ax ^= (n & 7) << 4;
    *(uint4*)(sWh + ax) = pack8(f0, f1);
  }
  // initial h
  #pragma unroll
  for (int c = 0; c < 2; ++c) {
    int id = c * 512 + tid;                 // 0..1023
    int m = id >> 6, nc = (id & 63) << 3;
    const float* src = h0 + (r0 + m) * DLAT + nc;
    float4 f0 = *(const float4*)src;
    float4 f1 = *(const float4*)(src + 4);
    int ax = (m << 10) + (nc << 1);
    ax ^= (m & 7) << 4;
    *(uint4*)(sH + ax) = pack8(f0, f1);
  }
  __syncthreads();

  const int nbase = w * 64 + (lq << 2);

  // prefetch xi for t = 0
  float4 xi[4];
  {
    const float* xr = HO + (long)(r0 + lm) * DLAT + nbase;
    #pragma unroll
    for (int t0 = 0; t0 < 4; ++t0) xi[t0] = *(const float4*)(xr + t0 * 16);
  }

  for (int t = 0; t < T_STEPS; ++t) {
    f32x4 acc[4];
    #pragma unroll
    for (int t0 = 0; t0 < 4; ++t0)
      acc[t0] = f32x4{xi[t0].x, xi[t0].y, xi[t0].z, xi[t0].w};

    // prefetch next xi (clamped at the end; values discarded)
    {
      long tn = (t + 1 < T_STEPS) ? (t + 1) : t;
      const float* xr = HO + (tn * BATCH + r0 + lm) * (long)DLAT + nbase;
      #pragma unroll
      for (int t0 = 0; t0 < 4; ++t0) xi[t0] = *(const float4*)(xr + t0 * 16);
    }

    // z^T[n][m] += sum_k Wh[n][k] * h[m][k]
    #pragma unroll
    for (int k0 = 0; k0 < 16; ++k0) {
      int kb = (k0 << 6) + (lq << 4);
      int ha = (lm << 10) + kb;
      ha ^= (lm & 7) << 4;
      bf16x8 hb = __builtin_bit_cast(bf16x8, *(uint4*)(sH + ha));
      if (k0 < 12) {
        #pragma unroll
        for (int t0 = 0; t0 < 4; ++t0)
          acc[t0] = __builtin_amdgcn_mfma_f32_16x16x32_bf16(
              __builtin_bit_cast(bf16x8, wreg[t0][k0]), hb, acc[t0], 0, 0, 0);
      } else {
        #pragma unroll
        for (int t0 = 0; t0 < 4; ++t0) {
          int n = w * 64 + t0 * 16 + lm;
          int wb = ((k0 - 12) << 6) + (lq << 4);
          int wa = (n << 8) + wb;
          wa ^= (n & 7) << 4;
          bf16x8 wf = __builtin_bit_cast(bf16x8, *(uint4*)(sWh + wa));
          acc[t0] = __builtin_amdgcn_mfma_f32_16x16x32_bf16(wf, hb, acc[t0], 0, 0, 0);
        }
      }
    }

    // tanh(z) = 1 - 2/(exp(2z)+1), computed in place (saves 16 live VGPRs)
    #pragma unroll
    for (int t0 = 0; t0 < 4; ++t0)
      #pragma unroll
      for (int e = 0; e < 4; ++e) {
        float z = acc[t0][e];
        float ex = __expf(2.0f * z);
        acc[t0][e] = 1.0f - 2.0f / (ex + 1.0f);
      }

    // store H[t] (fp32, float4 of 4 consecutive n)
    {
      float* orow = HO + ((long)t * BATCH + r0 + lm) * DLAT + nbase;
      #pragma unroll
      for (int t0 = 0; t0 < 4; ++t0) {
        float4 o;
        o.x = acc[t0][0]; o.y = acc[t0][1]; o.z = acc[t0][2]; o.w = acc[t0][3];
        *(float4*)(orow + t0 * 16) = o;
      }
    }

    __syncthreads();  // all h reads of this step done
    // write h_new (bf16) into sH
    #pragma unroll
    for (int t0 = 0; t0 < 4; ++t0) {
      int n = nbase + t0 * 16;
      int ax = (lm << 10) + (n << 1);
      ax ^= (lm & 7) << 4;
      uint2 v;
      v.x = f2bf2(acc[t0][0], acc[t0][1]);
      v.y = f2bf2(acc[t0][2], acc[t0][3]);
      *(uint2*)(sH + ax) = v;
    }
    __syncthreads();  // h ready for next step
  }
}

extern "C" void kernel_launch(void* const* d_in, const int* in_sizes, int n_in,
                              void* d_out, int out_size, void* d_ws, size_t ws_size,
                              hipStream_t stream) {
  const float* X  = (const float*)d_in[0];
  const float* h0 = (const float*)d_in[1];
  const float* Wi = (const float*)d_in[2];
  const float* bi = (const float*)d_in[3];
  const float* Wh = (const float*)d_in[4];
  const float* bh = (const float*)d_in[5];
  float* out = (float*)d_out;

  hipFuncSetAttribute((const void*)xi_gemm,  hipFuncAttributeMaxDynamicSharedMemorySize, 131584);
  hipFuncSetAttribute((const void*)rnn_scan, hipFuncAttributeMaxDynamicSharedMemorySize, 147456);

  xi_gemm<<<dim3(512, 4), 256, 131584, stream>>>(X, Wi, bi, bh, out);
  rnn_scan<<<8, 512, 147456, stream>>>(h0, Wh, out);
}

// Round 6
// 3245.455 us; speedup vs baseline: 1.1236x; 1.1236x over previous
//
#include <hip/hip_runtime.h>

#define T_STEPS 512
#define BATCH   128
#define DIN     256
#define DLAT    512

typedef __bf16 bf16x8 __attribute__((ext_vector_type(8)));
typedef float  f32x4  __attribute__((ext_vector_type(4)));

__device__ __forceinline__ unsigned int f2bf2(float a, float b) {
  unsigned int ua = __float_as_uint(a);
  unsigned int ub = __float_as_uint(b);
  ua = (ua + 0x7FFFu + ((ua >> 16) & 1u)) >> 16;
  ub = (ub + 0x7FFFu + ((ub >> 16) & 1u)) >> 16;
  return ua | (ub << 16);
}

__device__ __forceinline__ uint4 pack8(float4 f0, float4 f1) {
  uint4 r;
  r.x = f2bf2(f0.x, f0.y);
  r.y = f2bf2(f0.z, f0.w);
  r.z = f2bf2(f1.x, f1.y);
  r.w = f2bf2(f1.z, f1.w);
  return r;
}

// ---------------- Kernel A: Xi = X @ Wi^T + (bi + bh), written into d_out ----------------
// Tile 128x128, full K=256 staged in LDS as bf16 (swizzled), 4 waves of 64x64.
extern "C" __global__ __launch_bounds__(256) void xi_gemm(
    const float* __restrict__ X, const float* __restrict__ Wi,
    const float* __restrict__ bi, const float* __restrict__ bh,
    float* __restrict__ XiOut) {
  extern __shared__ char smem[];
  char*  sX    = smem;                      // 65536 B: [128 rows][512 B] swizzled
  char*  sW    = smem + 65536;              // 65536 B
  float* sBias = (float*)(smem + 131072);   // 128 floats

  const int tid = threadIdx.x;
  const long m0 = (long)blockIdx.x * 128;   // over T*B = 65536
  const int  n0 = blockIdx.y * 128;         // over DLAT

  #pragma unroll
  for (int c = 0; c < 16; ++c) {
    int id = c * 256 + tid;                 // 0..4095
    int r  = id >> 5;                       // 0..127
    int kc = (id & 31) << 3;                // 0..248
    const float* sx = X + (m0 + r) * DIN + kc;
    float4 a0 = *(const float4*)sx;
    float4 a1 = *(const float4*)(sx + 4);
    int ax = ((r << 9) + (kc << 1)) ^ ((r & 7) << 4);
    *(uint4*)(sX + ax) = pack8(a0, a1);
    const float* sw = Wi + (n0 + r) * DIN + kc;
    float4 b0 = *(const float4*)sw;
    float4 b1 = *(const float4*)(sw + 4);
    *(uint4*)(sW + ax) = pack8(b0, b1);
  }
  if (tid < 128) sBias[tid] = bi[n0 + tid] + bh[n0 + tid];
  __syncthreads();

  const int w = tid >> 6, lane = tid & 63;
  const int wm = (w >> 1) * 64, wn = (w & 1) * 64;
  const int lm = lane & 15, lq = lane >> 4;

  f32x4 acc[4][4];
  #pragma unroll
  for (int nt = 0; nt < 4; ++nt) {
    float bv = sBias[wn + nt * 16 + lm];
    #pragma unroll
    for (int mt = 0; mt < 4; ++mt) acc[mt][nt] = f32x4{bv, bv, bv, bv};
  }

  #pragma unroll
  for (int k0 = 0; k0 < 8; ++k0) {
    int kb = (k0 << 6) + (lq << 4);
    bf16x8 af[4], bfr[4];
    #pragma unroll
    for (int mt = 0; mt < 4; ++mt) {
      int row = wm + mt * 16 + lm;
      int ax = ((row << 9) + kb) ^ ((row & 7) << 4);
      af[mt] = __builtin_bit_cast(bf16x8, *(uint4*)(sX + ax));
    }
    #pragma unroll
    for (int nt = 0; nt < 4; ++nt) {
      int row = wn + nt * 16 + lm;
      int ax = ((row << 9) + kb) ^ ((row & 7) << 4);
      bfr[nt] = __builtin_bit_cast(bf16x8, *(uint4*)(sW + ax));
    }
    #pragma unroll
    for (int mt = 0; mt < 4; ++mt)
      #pragma unroll
      for (int nt = 0; nt < 4; ++nt)
        acc[mt][nt] = __builtin_amdgcn_mfma_f32_16x16x32_bf16(af[mt], bfr[nt], acc[mt][nt], 0, 0, 0);
  }

  #pragma unroll
  for (int mt = 0; mt < 4; ++mt) {
    #pragma unroll
    for (int e = 0; e < 4; ++e) {
      long m = m0 + wm + mt * 16 + (lq << 2) + e;
      float* dst = XiOut + m * DLAT + n0 + wn + lm;
      #pragma unroll
      for (int nt = 0; nt < 4; ++nt)
        dst[nt * 16] = acc[mt][nt][e];
    }
  }
}

// ---------------- Kernel B: persistent recurrence, 8 blocks x 16 batch rows ----------------
// 16 waves (1024 threads). Wave w owns n in [w*32, w*32+32) (2 MFMA n-tiles).
// Wh residency: k in [0,384) in registers -- wreg[2][12] = 96 VGPR/thread, fits the
// 128-reg cap a 1024-thread block gets (4 waves/EU). k in [384,512) in LDS (128 KB).
// Round-5 lesson (rule #21 family): swizzle XOR must be applied to the FULL address
// per access -- (base ^ mask) + k0*64 != (base + k0*64) ^ mask because k0*64 carries
// into the masked bit 6. All LDS reads below do (base + offset) ^ mask.
extern "C" __global__ __launch_bounds__(1024) void rnn_scan(
    const float* __restrict__ h0, const float* __restrict__ Wh,
    float* __restrict__ HO) {
  extern __shared__ char smem[];
  char* sWh = smem;             // 131072 B: [n=512][256 B], k in [384,512), swizzled
  char* sH  = smem + 131072;    // 16384 B:  [m=16][1024 B], swizzled

  const int tid = threadIdx.x;
  const int w = tid >> 6, lane = tid & 63;
  const int lm = lane & 15, lq = lane >> 4;
  const int r0 = blockIdx.x << 4;

  // Wh register fragments (A-operand): lane holds Wh[n = w*32+t0*16+lm][k0*32+8*lq .. +7]
  bf16x8 wreg[2][12];
  #pragma unroll
  for (int t0 = 0; t0 < 2; ++t0) {
    const float* base = Wh + (w * 32 + t0 * 16 + lm) * DLAT + (lq << 3);
    #pragma unroll
    for (int k0 = 0; k0 < 12; ++k0) {
      const float* src = base + k0 * 32;
      float4 f0 = *(const float4*)src;
      float4 f1 = *(const float4*)(src + 4);
      wreg[t0][k0] = __builtin_bit_cast(bf16x8, pack8(f0, f1));
    }
  }

  // Wh LDS region: k in [384,512). 512 rows x 16 chunks = 8192 -> 8 iters x 1024 threads.
  #pragma unroll
  for (int c = 0; c < 8; ++c) {
    int id = c * 1024 + tid;                // 0..8191
    int n = id >> 4, kc = (id & 15) << 3;   // kc 0..120
    const float* src = Wh + n * DLAT + 384 + kc;
    float4 f0 = *(const float4*)src;
    float4 f1 = *(const float4*)(src + 4);
    int ax = ((n << 8) + (kc << 1)) ^ ((n & 7) << 4);
    *(uint4*)(sWh + ax) = pack8(f0, f1);
  }
  // initial h: 16 rows x 64 chunks = 1024 -> 1 iter.
  {
    int m = tid >> 6, nc = (tid & 63) << 3;
    const float* src = h0 + (r0 + m) * DLAT + nc;
    float4 f0 = *(const float4*)src;
    float4 f1 = *(const float4*)(src + 4);
    int ax = ((m << 10) + (nc << 1)) ^ ((m & 7) << 4);
    *(uint4*)(sH + ax) = pack8(f0, f1);
  }
  __syncthreads();

  // Unswizzled bases; mask applied to full address per access.
  // (w*32+lm)&7 == lm&7 == (w*32+16+lm)&7, so one mask serves sH and both sWh rows.
  const int mask   = (lm & 7) << 4;
  const int hbase  = (lm << 10) + (lq << 4);
  const int wbase0 = ((w * 32 + lm) << 8) + (lq << 4);
  const int wbase1 = wbase0 + (16 << 8);
  const int ncol0  = w * 32 + (lq << 2);     // n of acc[0] elems (4 consecutive)

  // prefetch xi for t = 0
  float4 xi[2];
  {
    const float* xr = HO + (long)(r0 + lm) * DLAT + ncol0;
    xi[0] = *(const float4*)xr;
    xi[1] = *(const float4*)(xr + 16);
  }

  for (int t = 0; t < T_STEPS; ++t) {
    f32x4 acc[2];
    acc[0] = f32x4{xi[0].x, xi[0].y, xi[0].z, xi[0].w};
    acc[1] = f32x4{xi[1].x, xi[1].y, xi[1].z, xi[1].w};

    // prefetch next xi (clamped at the end; values discarded)
    {
      long tn = (t + 1 < T_STEPS) ? (t + 1) : t;
      const float* xr = HO + (tn * BATCH + r0 + lm) * (long)DLAT + ncol0;
      xi[0] = *(const float4*)xr;
      xi[1] = *(const float4*)(xr + 16);
    }

    // z^T[n][m] += sum_k Wh[n][k] * h[m][k]
    #pragma unroll
    for (int k0 = 0; k0 < 12; ++k0) {
      int ha = (hbase + k0 * 64) ^ mask;
      bf16x8 hb = __builtin_bit_cast(bf16x8, *(uint4*)(sH + ha));
      acc[0] = __builtin_amdgcn_mfma_f32_16x16x32_bf16(wreg[0][k0], hb, acc[0], 0, 0, 0);
      acc[1] = __builtin_amdgcn_mfma_f32_16x16x32_bf16(wreg[1][k0], hb, acc[1], 0, 0, 0);
    }
    #pragma unroll
    for (int k0 = 12; k0 < 16; ++k0) {
      int ha = (hbase + k0 * 64) ^ mask;
      bf16x8 hb = __builtin_bit_cast(bf16x8, *(uint4*)(sH + ha));
      int wa0 = (wbase0 + (k0 - 12) * 64) ^ mask;
      int wa1 = (wbase1 + (k0 - 12) * 64) ^ mask;
      bf16x8 wf0 = __builtin_bit_cast(bf16x8, *(uint4*)(sWh + wa0));
      bf16x8 wf1 = __builtin_bit_cast(bf16x8, *(uint4*)(sWh + wa1));
      acc[0] = __builtin_amdgcn_mfma_f32_16x16x32_bf16(wf0, hb, acc[0], 0, 0, 0);
      acc[1] = __builtin_amdgcn_mfma_f32_16x16x32_bf16(wf1, hb, acc[1], 0, 0, 0);
    }

    // tanh(z) = 1 - 2/(exp(2z)+1), in place
    #pragma unroll
    for (int t0 = 0; t0 < 2; ++t0)
      #pragma unroll
      for (int e = 0; e < 4; ++e) {
        float z = acc[t0][e];
        float ex = __expf(2.0f * z);
        acc[t0][e] = 1.0f - 2.0f / (ex + 1.0f);
      }

    // store H[t] (fp32, two float4 of 4 consecutive n)
    {
      float* orow = HO + ((long)t * BATCH + r0 + lm) * DLAT + ncol0;
      float4 o0; o0.x = acc[0][0]; o0.y = acc[0][1]; o0.z = acc[0][2]; o0.w = acc[0][3];
      float4 o1; o1.x = acc[1][0]; o1.y = acc[1][1]; o1.z = acc[1][2]; o1.w = acc[1][3];
      *(float4*)orow = o0;
      *(float4*)(orow + 16) = o1;
    }

    __syncthreads();  // all h reads of this step done
    // write h_new (bf16) into sH: row lm, cols ncol0..+3 and +16..+19
    #pragma unroll
    for (int t0 = 0; t0 < 2; ++t0) {
      int n = ncol0 + t0 * 16;
      int ax = ((lm << 10) + (n << 1)) ^ mask;
      uint2 v;
      v.x = f2bf2(acc[t0][0], acc[t0][1]);
      v.y = f2bf2(acc[t0][2], acc[t0][3]);
      *(uint2*)(sH + ax) = v;
    }
    __syncthreads();  // h ready for next step
  }
}

extern "C" void kernel_launch(void* const* d_in, const int* in_sizes, int n_in,
                              void* d_out, int out_size, void* d_ws, size_t ws_size,
                              hipStream_t stream) {
  const float* X  = (const float*)d_in[0];
  const float* h0 = (const float*)d_in[1];
  const float* Wi = (const float*)d_in[2];
  const float* bi = (const float*)d_in[3];
  const float* Wh = (const float*)d_in[4];
  const float* bh = (const float*)d_in[5];
  float* out = (float*)d_out;

  hipFuncSetAttribute((const void*)xi_gemm,  hipFuncAttributeMaxDynamicSharedMemorySize, 131584);
  hipFuncSetAttribute((const void*)rnn_scan, hipFuncAttributeMaxDynamicSharedMemorySize, 147456);

  xi_gemm<<<dim3(512, 4), 256, 131584, stream>>>(X, Wi, bi, bh, out);
  rnn_scan<<<8, 1024, 147456, stream>>>(h0, Wh, out);
}

// Round 7
// 2536.683 us; speedup vs baseline: 1.4375x; 1.2794x over previous
//
#include <hip/hip_runtime.h>

#define T_STEPS 512
#define BATCH   128
#define DIN     256
#define DLAT    512

typedef __bf16 bf16x8 __attribute__((ext_vector_type(8)));
typedef float  f32x4  __attribute__((ext_vector_type(4)));
typedef int    i32x4  __attribute__((ext_vector_type(4)));

__device__ __forceinline__ unsigned int f2bf2(float a, float b) {
  unsigned int ua = __float_as_uint(a);
  unsigned int ub = __float_as_uint(b);
  ua = (ua + 0x7FFFu + ((ua >> 16) & 1u)) >> 16;
  ub = (ub + 0x7FFFu + ((ub >> 16) & 1u)) >> 16;
  return ua | (ub << 16);
}

__device__ __forceinline__ uint4 pack8(float4 f0, float4 f1) {
  uint4 r;
  r.x = f2bf2(f0.x, f0.y);
  r.y = f2bf2(f0.z, f0.w);
  r.z = f2bf2(f1.x, f1.y);
  r.w = f2bf2(f1.z, f1.w);
  return r;
}

// ---------------- Kernel P: prepack Wh fp32 -> bf16 row-major in workspace ----------------
extern "C" __global__ __launch_bounds__(256) void pk_wh(
    const float* __restrict__ Wh, unsigned int* __restrict__ out) {
  int idx = blockIdx.x * 256 + threadIdx.x;   // 0..32767, 8 f32 each
  const float* src = Wh + (long)idx * 8;
  float4 f0 = *(const float4*)src;
  float4 f1 = *(const float4*)(src + 4);
  uint4 v = pack8(f0, f1);
  *(uint4*)(out + (long)idx * 4) = v;
}

// ---------------- Kernel A: Xi = X @ Wi^T + (bi + bh), written into d_out ----------------
extern "C" __global__ __launch_bounds__(256) void xi_gemm(
    const float* __restrict__ X, const float* __restrict__ Wi,
    const float* __restrict__ bi, const float* __restrict__ bh,
    float* __restrict__ XiOut) {
  extern __shared__ char smem[];
  char*  sX    = smem;                      // 65536 B: [128 rows][512 B] swizzled
  char*  sW    = smem + 65536;              // 65536 B
  float* sBias = (float*)(smem + 131072);   // 128 floats

  const int tid = threadIdx.x;
  const long m0 = (long)blockIdx.x * 128;   // over T*B = 65536
  const int  n0 = blockIdx.y * 128;         // over DLAT

  #pragma unroll
  for (int c = 0; c < 16; ++c) {
    int id = c * 256 + tid;                 // 0..4095
    int r  = id >> 5;                       // 0..127
    int kc = (id & 31) << 3;                // 0..248
    const float* sx = X + (m0 + r) * DIN + kc;
    float4 a0 = *(const float4*)sx;
    float4 a1 = *(const float4*)(sx + 4);
    int ax = ((r << 9) + (kc << 1)) ^ ((r & 7) << 4);
    *(uint4*)(sX + ax) = pack8(a0, a1);
    const float* sw = Wi + (n0 + r) * DIN + kc;
    float4 b0 = *(const float4*)sw;
    float4 b1 = *(const float4*)(sw + 4);
    *(uint4*)(sW + ax) = pack8(b0, b1);
  }
  if (tid < 128) sBias[tid] = bi[n0 + tid] + bh[n0 + tid];
  __syncthreads();

  const int w = tid >> 6, lane = tid & 63;
  const int wm = (w >> 1) * 64, wn = (w & 1) * 64;
  const int lm = lane & 15, lq = lane >> 4;

  f32x4 acc[4][4];
  #pragma unroll
  for (int nt = 0; nt < 4; ++nt) {
    float bv = sBias[wn + nt * 16 + lm];
    #pragma unroll
    for (int mt = 0; mt < 4; ++mt) acc[mt][nt] = f32x4{bv, bv, bv, bv};
  }

  #pragma unroll
  for (int k0 = 0; k0 < 8; ++k0) {
    int kb = (k0 << 6) + (lq << 4);
    bf16x8 af[4], bfr[4];
    #pragma unroll
    for (int mt = 0; mt < 4; ++mt) {
      int row = wm + mt * 16 + lm;
      int ax = ((row << 9) + kb) ^ ((row & 7) << 4);
      af[mt] = __builtin_bit_cast(bf16x8, *(uint4*)(sX + ax));
    }
    #pragma unroll
    for (int nt = 0; nt < 4; ++nt) {
      int row = wn + nt * 16 + lm;
      int ax = ((row << 9) + kb) ^ ((row & 7) << 4);
      bfr[nt] = __builtin_bit_cast(bf16x8, *(uint4*)(sW + ax));
    }
    #pragma unroll
    for (int mt = 0; mt < 4; ++mt)
      #pragma unroll
      for (int nt = 0; nt < 4; ++nt)
        acc[mt][nt] = __builtin_amdgcn_mfma_f32_16x16x32_bf16(af[mt], bfr[nt], acc[mt][nt], 0, 0, 0);
  }

  #pragma unroll
  for (int mt = 0; mt < 4; ++mt) {
    #pragma unroll
    for (int e = 0; e < 4; ++e) {
      long m = m0 + wm + mt * 16 + (lq << 2) + e;
      float* dst = XiOut + m * DLAT + n0 + wn + lm;
      #pragma unroll
      for (int nt = 0; nt < 4; ++nt)
        dst[nt * 16] = acc[mt][nt][e];
    }
  }
}

// ---------------- Kernel B: persistent recurrence, 8 blocks x 16 batch rows ----------------
// 16 waves. Wave w owns n in [w*32, w*32+32). wreg[2][12] = 96 VGPR holds k in [0,384);
// k in [384,512) in LDS. Rounds 2-6 root cause: compiler can't see dynamic LDS ->
// occupancy heuristic caps VGPRs (64!) -> invariant-memory loads get REMATERIALIZED
// every timestep (VALUBusy 76%). Fix: (a) amdgpu_waves_per_eu(4,4) = our true occupancy,
// budget 512 regs/wave; (b) empty-asm "+v" pins INSIDE the t-loop make wreg loop-carried
// asm defs -- LLVM cannot remat those; (c) Wh prepacked to bf16 in ws so init is pure
// 16-B loads (no pack chains to tempt remat).
extern "C" __global__ __launch_bounds__(1024)
__attribute__((amdgpu_waves_per_eu(4, 4)))
void rnn_scan(
    const float* __restrict__ h0, const unsigned short* __restrict__ WhP,
    float* __restrict__ HO) {
  extern __shared__ char smem[];
  char* sWh = smem;             // 131072 B: [n=512][256 B], k in [384,512), swizzled
  char* sH  = smem + 131072;    // 16384 B:  [m=16][1024 B], swizzled

  const int tid = threadIdx.x;
  const int w = tid >> 6, lane = tid & 63;
  const int lm = lane & 15, lq = lane >> 4;
  const int r0 = blockIdx.x << 4;

  // Wh register fragments: lane holds Wh[n = w*32+t0*16+lm][k0*32+8*lq .. +7] (bf16)
  i32x4 wreg[2][12];
  #pragma unroll
  for (int t0 = 0; t0 < 2; ++t0) {
    const unsigned short* base = WhP + (w * 32 + t0 * 16 + lm) * DLAT + (lq << 3);
    #pragma unroll
    for (int k0 = 0; k0 < 12; ++k0)
      wreg[t0][k0] = *(const i32x4*)(base + k0 * 32);
  }

  // Wh LDS region: k in [384,512). 512 rows x 16 chunks = 8192 -> 8 iters x 1024 threads.
  #pragma unroll
  for (int c = 0; c < 8; ++c) {
    int id = c * 1024 + tid;                // 0..8191
    int n = id >> 4, kc = (id & 15) << 3;   // kc 0..120
    uint4 v = *(const uint4*)(WhP + n * DLAT + 384 + kc);
    int ax = ((n << 8) + (kc << 1)) ^ ((n & 7) << 4);
    *(uint4*)(sWh + ax) = v;
  }
  // initial h: 16 rows x 64 chunks = 1024 -> 1 iter.
  {
    int m = tid >> 6, nc = (tid & 63) << 3;
    const float* src = h0 + (r0 + m) * DLAT + nc;
    float4 f0 = *(const float4*)src;
    float4 f1 = *(const float4*)(src + 4);
    int ax = ((m << 10) + (nc << 1)) ^ ((m & 7) << 4);
    *(uint4*)(sH + ax) = pack8(f0, f1);
  }
  __syncthreads();

  // Unswizzled bases; XOR mask applied to the FULL address per access (round-5 lesson).
  const int mask   = (lm & 7) << 4;
  const int hbase  = (lm << 10) + (lq << 4);
  const int wbase0 = ((w * 32 + lm) << 8) + (lq << 4);
  const int wbase1 = wbase0 + (16 << 8);
  const int ncol0  = w * 32 + (lq << 2);     // n of acc[0] elems (4 consecutive)

  // prefetch xi for t = 0
  float4 xi[2];
  {
    const float* xr = HO + (long)(r0 + lm) * DLAT + ncol0;
    xi[0] = *(const float4*)xr;
    xi[1] = *(const float4*)(xr + 16);
  }

  for (int t = 0; t < T_STEPS; ++t) {
    // Loop-carried identity pins: wreg becomes an asm def each iteration ->
    // not rematerializable; allocator must keep it live (budget is there).
    #pragma unroll
    for (int t0 = 0; t0 < 2; ++t0)
      #pragma unroll
      for (int k0 = 0; k0 < 12; ++k0)
        asm("" : "+v"(wreg[t0][k0]));

    f32x4 acc[2];
    acc[0] = f32x4{xi[0].x, xi[0].y, xi[0].z, xi[0].w};
    acc[1] = f32x4{xi[1].x, xi[1].y, xi[1].z, xi[1].w};

    // prefetch next xi (clamped at the end; values discarded)
    {
      long tn = (t + 1 < T_STEPS) ? (t + 1) : t;
      const float* xr = HO + (tn * BATCH + r0 + lm) * (long)DLAT + ncol0;
      xi[0] = *(const float4*)xr;
      xi[1] = *(const float4*)(xr + 16);
    }

    // z^T[n][m] += sum_k Wh[n][k] * h[m][k]
    #pragma unroll
    for (int k0 = 0; k0 < 12; ++k0) {
      int ha = (hbase + k0 * 64) ^ mask;
      bf16x8 hb = __builtin_bit_cast(bf16x8, *(uint4*)(sH + ha));
      acc[0] = __builtin_amdgcn_mfma_f32_16x16x32_bf16(
          __builtin_bit_cast(bf16x8, wreg[0][k0]), hb, acc[0], 0, 0, 0);
      acc[1] = __builtin_amdgcn_mfma_f32_16x16x32_bf16(
          __builtin_bit_cast(bf16x8, wreg[1][k0]), hb, acc[1], 0, 0, 0);
    }
    #pragma unroll
    for (int k0 = 12; k0 < 16; ++k0) {
      int ha = (hbase + k0 * 64) ^ mask;
      bf16x8 hb = __builtin_bit_cast(bf16x8, *(uint4*)(sH + ha));
      int wa0 = (wbase0 + (k0 - 12) * 64) ^ mask;
      int wa1 = (wbase1 + (k0 - 12) * 64) ^ mask;
      bf16x8 wf0 = __builtin_bit_cast(bf16x8, *(uint4*)(sWh + wa0));
      bf16x8 wf1 = __builtin_bit_cast(bf16x8, *(uint4*)(sWh + wa1));
      acc[0] = __builtin_amdgcn_mfma_f32_16x16x32_bf16(wf0, hb, acc[0], 0, 0, 0);
      acc[1] = __builtin_amdgcn_mfma_f32_16x16x32_bf16(wf1, hb, acc[1], 0, 0, 0);
    }

    // tanh(z) = 1 - 2/(exp(2z)+1), in place
    #pragma unroll
    for (int t0 = 0; t0 < 2; ++t0)
      #pragma unroll
      for (int e = 0; e < 4; ++e) {
        float z = acc[t0][e];
        float ex = __expf(2.0f * z);
        acc[t0][e] = 1.0f - 2.0f / (ex + 1.0f);
      }

    // store H[t] (fp32, two float4 of 4 consecutive n)
    {
      float* orow = HO + ((long)t * BATCH + r0 + lm) * DLAT + ncol0;
      float4 o0; o0.x = acc[0][0]; o0.y = acc[0][1]; o0.z = acc[0][2]; o0.w = acc[0][3];
      float4 o1; o1.x = acc[1][0]; o1.y = acc[1][1]; o1.z = acc[1][2]; o1.w = acc[1][3];
      *(float4*)orow = o0;
      *(float4*)(orow + 16) = o1;
    }

    __syncthreads();  // all h reads of this step done
    // write h_new (bf16) into sH: row lm, cols ncol0..+3 and +16..+19
    #pragma unroll
    for (int t0 = 0; t0 < 2; ++t0) {
      int n = ncol0 + t0 * 16;
      int ax = ((lm << 10) + (n << 1)) ^ mask;
      uint2 v;
      v.x = f2bf2(acc[t0][0], acc[t0][1]);
      v.y = f2bf2(acc[t0][2], acc[t0][3]);
      *(uint2*)(sH + ax) = v;
    }
    __syncthreads();  // h ready for next step
  }
}

extern "C" void kernel_launch(void* const* d_in, const int* in_sizes, int n_in,
                              void* d_out, int out_size, void* d_ws, size_t ws_size,
                              hipStream_t stream) {
  const float* X  = (const float*)d_in[0];
  const float* h0 = (const float*)d_in[1];
  const float* Wi = (const float*)d_in[2];
  const float* bi = (const float*)d_in[3];
  const float* Wh = (const float*)d_in[4];
  const float* bh = (const float*)d_in[5];
  float* out = (float*)d_out;
  unsigned int* whp = (unsigned int*)d_ws;   // 512 KB bf16 Wh

  hipFuncSetAttribute((const void*)xi_gemm,  hipFuncAttributeMaxDynamicSharedMemorySize, 131584);
  hipFuncSetAttribute((const void*)rnn_scan, hipFuncAttributeMaxDynamicSharedMemorySize, 147456);

  pk_wh<<<128, 256, 0, stream>>>(Wh, whp);
  xi_gemm<<<dim3(512, 4), 256, 131584, stream>>>(X, Wi, bi, bh, out);
  rnn_scan<<<8, 1024, 147456, stream>>>(h0, (const unsigned short*)whp, out);
}

// Round 8
// 2535.415 us; speedup vs baseline: 1.4382x; 1.0005x over previous
//
#include <hip/hip_runtime.h>

#define T_STEPS 512
#define BATCH   128
#define DIN     256
#define DLAT    512

typedef __bf16 bf16x8 __attribute__((ext_vector_type(8)));
typedef float  f32x4  __attribute__((ext_vector_type(4)));
typedef int    i32x4  __attribute__((ext_vector_type(4)));

__device__ __forceinline__ unsigned int f2bf2(float a, float b) {
  unsigned int ua = __float_as_uint(a);
  unsigned int ub = __float_as_uint(b);
  ua = (ua + 0x7FFFu + ((ua >> 16) & 1u)) >> 16;
  ub = (ub + 0x7FFFu + ((ub >> 16) & 1u)) >> 16;
  return ua | (ub << 16);
}

__device__ __forceinline__ uint4 pack8(float4 f0, float4 f1) {
  uint4 r;
  r.x = f2bf2(f0.x, f0.y);
  r.y = f2bf2(f0.z, f0.w);
  r.z = f2bf2(f1.x, f1.y);
  r.w = f2bf2(f1.z, f1.w);
  return r;
}

// ---------------- Kernel P: prepack Wh fp32 -> bf16 row-major in workspace ----------------
extern "C" __global__ __launch_bounds__(256) void pk_wh(
    const float* __restrict__ Wh, unsigned int* __restrict__ out) {
  int idx = blockIdx.x * 256 + threadIdx.x;   // 0..32767, 8 f32 each
  const float* src = Wh + (long)idx * 8;
  float4 f0 = *(const float4*)src;
  float4 f1 = *(const float4*)(src + 4);
  uint4 v = pack8(f0, f1);
  *(uint4*)(out + (long)idx * 4) = v;
}

// ---------------- Kernel A: Xi = X @ Wi^T + (bi + bh), written into d_out ----------------
extern "C" __global__ __launch_bounds__(256) void xi_gemm(
    const float* __restrict__ X, const float* __restrict__ Wi,
    const float* __restrict__ bi, const float* __restrict__ bh,
    float* __restrict__ XiOut) {
  extern __shared__ char smem[];
  char*  sX    = smem;                      // 65536 B: [128 rows][512 B] swizzled
  char*  sW    = smem + 65536;              // 65536 B
  float* sBias = (float*)(smem + 131072);   // 128 floats

  const int tid = threadIdx.x;
  const long m0 = (long)blockIdx.x * 128;   // over T*B = 65536
  const int  n0 = blockIdx.y * 128;         // over DLAT

  #pragma unroll
  for (int c = 0; c < 16; ++c) {
    int id = c * 256 + tid;                 // 0..4095
    int r  = id >> 5;                       // 0..127
    int kc = (id & 31) << 3;                // 0..248
    const float* sx = X + (m0 + r) * DIN + kc;
    float4 a0 = *(const float4*)sx;
    float4 a1 = *(const float4*)(sx + 4);
    int ax = ((r << 9) + (kc << 1)) ^ ((r & 7) << 4);
    *(uint4*)(sX + ax) = pack8(a0, a1);
    const float* sw = Wi + (n0 + r) * DIN + kc;
    float4 b0 = *(const float4*)sw;
    float4 b1 = *(const float4*)(sw + 4);
    *(uint4*)(sW + ax) = pack8(b0, b1);
  }
  if (tid < 128) sBias[tid] = bi[n0 + tid] + bh[n0 + tid];
  __syncthreads();

  const int w = tid >> 6, lane = tid & 63;
  const int wm = (w >> 1) * 64, wn = (w & 1) * 64;
  const int lm = lane & 15, lq = lane >> 4;

  f32x4 acc[4][4];
  #pragma unroll
  for (int nt = 0; nt < 4; ++nt) {
    float bv = sBias[wn + nt * 16 + lm];
    #pragma unroll
    for (int mt = 0; mt < 4; ++mt) acc[mt][nt] = f32x4{bv, bv, bv, bv};
  }

  #pragma unroll
  for (int k0 = 0; k0 < 8; ++k0) {
    int kb = (k0 << 6) + (lq << 4);
    bf16x8 af[4], bfr[4];
    #pragma unroll
    for (int mt = 0; mt < 4; ++mt) {
      int row = wm + mt * 16 + lm;
      int ax = ((row << 9) + kb) ^ ((row & 7) << 4);
      af[mt] = __builtin_bit_cast(bf16x8, *(uint4*)(sX + ax));
    }
    #pragma unroll
    for (int nt = 0; nt < 4; ++nt) {
      int row = wn + nt * 16 + lm;
      int ax = ((row << 9) + kb) ^ ((row & 7) << 4);
      bfr[nt] = __builtin_bit_cast(bf16x8, *(uint4*)(sW + ax));
    }
    #pragma unroll
    for (int mt = 0; mt < 4; ++mt)
      #pragma unroll
      for (int nt = 0; nt < 4; ++nt)
        acc[mt][nt] = __builtin_amdgcn_mfma_f32_16x16x32_bf16(af[mt], bfr[nt], acc[mt][nt], 0, 0, 0);
  }

  #pragma unroll
  for (int mt = 0; mt < 4; ++mt) {
    #pragma unroll
    for (int e = 0; e < 4; ++e) {
      long m = m0 + wm + mt * 16 + (lq << 2) + e;
      float* dst = XiOut + m * DLAT + n0 + wn + lm;
      #pragma unroll
      for (int nt = 0; nt < 4; ++nt)
        dst[nt * 16] = acc[mt][nt][e];
    }
  }
}

// ---------------- Kernel B: persistent recurrence, 8 blocks x 16 batch rows ----------------
// 16 waves. Wave w owns n in [w*32, w*32+32). wreg[2][12] = 96 VGPR holds k in [0,384);
// k in [384,512) in LDS. Rounds 2-6 root cause: compiler can't see dynamic LDS ->
// occupancy heuristic caps VGPRs (64!) -> invariant-memory loads get REMATERIALIZED
// every timestep (VALUBusy 76%). Fix: (a) amdgpu_waves_per_eu(4,4) = our true occupancy,
// budget 512 regs/wave; (b) empty-asm "+v" pins INSIDE the t-loop make wreg loop-carried
// asm defs -- LLVM cannot remat those; (c) Wh prepacked to bf16 in ws so init is pure
// 16-B loads (no pack chains to tempt remat).
extern "C" __global__ __launch_bounds__(1024)
__attribute__((amdgpu_waves_per_eu(4, 4)))
void rnn_scan(
    const float* __restrict__ h0, const unsigned short* __restrict__ WhP,
    float* __restrict__ HO) {
  extern __shared__ char smem[];
  char* sWh = smem;             // 131072 B: [n=512][256 B], k in [384,512), swizzled
  char* sH  = smem + 131072;    // 16384 B:  [m=16][1024 B], swizzled

  const int tid = threadIdx.x;
  const int w = tid >> 6, lane = tid & 63;
  const int lm = lane & 15, lq = lane >> 4;
  const int r0 = blockIdx.x << 4;

  // Wh register fragments: lane holds Wh[n = w*32+t0*16+lm][k0*32+8*lq .. +7] (bf16)
  i32x4 wreg[2][12];
  #pragma unroll
  for (int t0 = 0; t0 < 2; ++t0) {
    const unsigned short* base = WhP + (w * 32 + t0 * 16 + lm) * DLAT + (lq << 3);
    #pragma unroll
    for (int k0 = 0; k0 < 12; ++k0)
      wreg[t0][k0] = *(const i32x4*)(base + k0 * 32);
  }

  // Wh LDS region: k in [384,512). 512 rows x 16 chunks = 8192 -> 8 iters x 1024 threads.
  #pragma unroll
  for (int c = 0; c < 8; ++c) {
    int id = c * 1024 + tid;                // 0..8191
    int n = id >> 4, kc = (id & 15) << 3;   // kc 0..120
    uint4 v = *(const uint4*)(WhP + n * DLAT + 384 + kc);
    int ax = ((n << 8) + (kc << 1)) ^ ((n & 7) << 4);
    *(uint4*)(sWh + ax) = v;
  }
  // initial h: 16 rows x 64 chunks = 1024 -> 1 iter.
  {
    int m = tid >> 6, nc = (tid & 63) << 3;
    const float* src = h0 + (r0 + m) * DLAT + nc;
    float4 f0 = *(const float4*)src;
    float4 f1 = *(const float4*)(src + 4);
    int ax = ((m << 10) + (nc << 1)) ^ ((m & 7) << 4);
    *(uint4*)(sH + ax) = pack8(f0, f1);
  }
  __syncthreads();

  // Unswizzled bases; XOR mask applied to the FULL address per access (round-5 lesson).
  const int mask   = (lm & 7) << 4;
  const int hbase  = (lm << 10) + (lq << 4);
  const int wbase0 = ((w * 32 + lm) << 8) + (lq << 4);
  const int wbase1 = wbase0 + (16 << 8);
  const int ncol0  = w * 32 + (lq << 2);     // n of acc[0] elems (4 consecutive)

  // prefetch xi for t = 0
  float4 xi[2];
  {
    const float* xr = HO + (long)(r0 + lm) * DLAT + ncol0;
    xi[0] = *(const float4*)xr;
    xi[1] = *(const float4*)(xr + 16);
  }

  for (int t = 0; t < T_STEPS; ++t) {
    // Loop-carried identity pins: wreg becomes an asm def each iteration ->
    // not rematerializable; allocator must keep it live (budget is there).
    #pragma unroll
    for (int t0 = 0; t0 < 2; ++t0)
      #pragma unroll
      for (int k0 = 0; k0 < 12; ++k0)
        asm("" : "+v"(wreg[t0][k0]));

    f32x4 acc[2];
    acc[0] = f32x4{xi[0].x, xi[0].y, xi[0].z, xi[0].w};
    acc[1] = f32x4{xi[1].x, xi[1].y, xi[1].z, xi[1].w};

    // prefetch next xi (clamped at the end; values discarded)
    {
      long tn = (t + 1 < T_STEPS) ? (t + 1) : t;
      const float* xr = HO + (tn * BATCH + r0 + lm) * (long)DLAT + ncol0;
      xi[0] = *(const float4*)xr;
      xi[1] = *(const float4*)(xr + 16);
    }

    // z^T[n][m] += sum_k Wh[n][k] * h[m][k]
    #pragma unroll
    for (int k0 = 0; k0 < 12; ++k0) {
      int ha = (hbase + k0 * 64) ^ mask;
      bf16x8 hb = __builtin_bit_cast(bf16x8, *(uint4*)(sH + ha));
      acc[0] = __builtin_amdgcn_mfma_f32_16x16x32_bf16(
          __builtin_bit_cast(bf16x8, wreg[0][k0]), hb, acc[0], 0, 0, 0);
      acc[1] = __builtin_amdgcn_mfma_f32_16x16x32_bf16(
          __builtin_bit_cast(bf16x8, wreg[1][k0]), hb, acc[1], 0, 0, 0);
    }
    #pragma unroll
    for (int k0 = 12; k0 < 16; ++k0) {
      int ha = (hbase + k0 * 64) ^ mask;
      bf16x8 hb = __builtin_bit_cast(bf16x8, *(uint4*)(sH + ha));
      int wa0 = (wbase0 + (k0 - 12) * 64) ^ mask;
      int wa1 = (wbase1 + (k0 - 12) * 64) ^ mask;
      bf16x8 wf0 = __builtin_bit_cast(bf16x8, *(uint4*)(sWh + wa0));
      bf16x8 wf1 = __builtin_bit_cast(bf16x8, *(uint4*)(sWh + wa1));
      acc[0] = __builtin_amdgcn_mfma_f32_16x16x32_bf16(wf0, hb, acc[0], 0, 0, 0);
      acc[1] = __builtin_amdgcn_mfma_f32_16x16x32_bf16(wf1, hb, acc[1], 0, 0, 0);
    }

    // tanh(z) = 1 - 2/(exp(2z)+1), in place
    #pragma unroll
    for (int t0 = 0; t0 < 2; ++t0)
      #pragma unroll
      for (int e = 0; e < 4; ++e) {
        float z = acc[t0][e];
        float ex = __expf(2.0f * z);
        acc[t0][e] = 1.0f - 2.0f / (ex + 1.0f);
      }

    // store H[t] (fp32, two float4 of 4 consecutive n)
    {
      float* orow = HO + ((long)t * BATCH + r0 + lm) * DLAT + ncol0;
      float4 o0; o0.x = acc[0][0]; o0.y = acc[0][1]; o0.z = acc[0][2]; o0.w = acc[0][3];
      float4 o1; o1.x = acc[1][0]; o1.y = acc[1][1]; o1.z = acc[1][2]; o1.w = acc[1][3];
      *(float4*)orow = o0;
      *(float4*)(orow + 16) = o1;
    }

    __syncthreads();  // all h reads of this step done
    // write h_new (bf16) into sH: row lm, cols ncol0..+3 and +16..+19
    #pragma unroll
    for (int t0 = 0; t0 < 2; ++t0) {
      int n = ncol0 + t0 * 16;
      int ax = ((lm << 10) + (n << 1)) ^ mask;
      uint2 v;
      v.x = f2bf2(acc[t0][0], acc[t0][1]);
      v.y = f2bf2(acc[t0][2], acc[t0][3]);
      *(uint2*)(sH + ax) = v;
    }
    __syncthreads();  // h ready for next step
  }
}

extern "C" void kernel_launch(void* const* d_in, const int* in_sizes, int n_in,
                              void* d_out, int out_size, void* d_ws, size_t ws_size,
                              hipStream_t stream) {
  const float* X  = (const float*)d_in[0];
  const float* h0 = (const float*)d_in[1];
  const float* Wi = (const float*)d_in[2];
  const float* bi = (const float*)d_in[3];
  const float* Wh = (const float*)d_in[4];
  const float* bh = (const float*)d_in[5];
  float* out = (float*)d_out;
  unsigned int* whp = (unsigned int*)d_ws;   // 512 KB bf16 Wh

  hipFuncSetAttribute((const void*)xi_gemm,  hipFuncAttributeMaxDynamicSharedMemorySize, 131584);
  hipFuncSetAttribute((const void*)rnn_scan, hipFuncAttributeMaxDynamicSharedMemorySize, 147456);

  pk_wh<<<128, 256, 0, stream>>>(Wh, whp);
  xi_gemm<<<dim3(512, 4), 256, 131584, stream>>>(X, Wi, bi, bh, out);
  rnn_scan<<<8, 1024, 147456, stream>>>(h0, (const unsigned short*)whp, out);
}